// Round 5
// baseline (339.765 us; speedup 1.0000x reference)
//
#include <hip/hip_runtime.h>
#include <hip/hip_bf16.h>
#include <stdint.h>

typedef short s16x8 __attribute__((ext_vector_type(8)));
typedef float f32x4 __attribute__((ext_vector_type(4)));

#define NH    32
#define NKVH  8
#define GQ    4
#define HD    128
#define QBLK  32
#define KVBLK 64

static __device__ __forceinline__ ushort f2bf(float f) {
  return __bfloat16_as_ushort(__float2bfloat16(f));
}

static __device__ __forceinline__ int swzV(int d) {
  return (((d & 7) ^ ((d >> 4) & 7)) << 3);
}

__global__ void __launch_bounds__(256, 2)
attn_doc_causal(const float* __restrict__ qg, const float* __restrict__ kg,
                const float* __restrict__ vg, float* __restrict__ og,
                int S, int L) {
  __shared__ ushort Klds[KVBLK * HD];     // [kv][d], ^((kv&7)<<3)
  __shared__ ushort Vt[HD * KVBLK];       // [d][kv], ^swzV(d)
  __shared__ ushort Plds[4][32 * KVBLK];  // per-wave [q][kv], ^(((q>>1)&7)<<3)

  const int tid  = threadIdx.x;
  const int lane = tid & 63;
  const int wid  = tid >> 6;               // 0..3 = GQA head within group
  const int col  = lane & 15;
  const int hi   = lane >> 4;
  const int bid  = blockIdx.x;
  const int kvh  = bid & 7;                // head-aligned XCD mapping
  const int nq   = L / QBLK;               // 32
  const int npair= nq >> 1;                // 16
  const int pidx = bid >> 3;
  const int doc  = pidx / npair;
  const int ipr  = pidx % npair;
  const int doc0 = doc * L;
  const int h    = kvh * GQ + wid;

  const int qt0   = nq - 1 - ipr;          // big q-tile first
  const int qt1   = ipr;
  const int nt0   = qt0 / 2 + 1;           // KVBLK=2*QBLK
  const int nt1   = qt1 / 2 + 1;
  const int total = nt0 + nt1;             // == 17, uniform
  const int qw0   = doc0 + qt0 * QBLK;
  const int qw1   = doc0 + qt1 * QBLK;
  const int moff0 = (qt0 & 1) << 5;        // diag mask offset
  const int moff1 = (qt1 & 1) << 5;

  const float cs  = 0.08838834764831845f * 1.4426950408889634f;  // SCALE*log2(e)
  const float THR = 62.0f;

  // staging assignments
  const int srow  = tid >> 2;              // K row 0..63
  const int scolK = (tid & 3) << 5;        // K col0 {0,32,64,96} floats
  const int vd0   = (tid & 31) << 2;       // V: 4 d's
  const int vkv0  = (tid >> 5) << 3;       // V: 8 kv's
  const size_t kvstr = (size_t)(NKVH * HD);

  s16x8 qf[2][4];
  auto loadQ = [&](int qw) {
#pragma unroll
    for (int st = 0; st < 2; ++st) {
      const float* qrow = qg + (size_t)(qw + st * 16 + col) * (NH * HD) + h * HD + hi * 8;
#pragma unroll
      for (int dc = 0; dc < 4; ++dc) {
        float4 x = ((const float4*)(qrow + dc * 32))[0];
        float4 y = ((const float4*)(qrow + dc * 32))[1];
        s16x8 f;
        f[0] = (short)f2bf(x.x); f[1] = (short)f2bf(x.y);
        f[2] = (short)f2bf(x.z); f[3] = (short)f2bf(x.w);
        f[4] = (short)f2bf(y.x); f[5] = (short)f2bf(y.y);
        f[6] = (short)f2bf(y.z); f[7] = (short)f2bf(y.w);
        qf[st][dc] = f;
      }
    }
  };

  float4 kk[8], vv[8];
  auto loadKV = [&](int r0) {  // r0 = global kv row of tile start
    const float* ks = kg + (size_t)(r0 + srow) * kvstr + kvh * HD + scolK;
#pragma unroll
    for (int j = 0; j < 8; ++j) kk[j] = ((const float4*)ks)[j];
    const float* vs = vg + (size_t)kvh * HD + vd0;
#pragma unroll
    for (int r = 0; r < 8; ++r)
      vv[r] = *(const float4*)(vs + (size_t)(r0 + vkv0 + r) * kvstr);
  };

  auto stage = [&]() {
    const int swK = (srow & 7) << 3;
#pragma unroll
    for (int c = 0; c < 4; ++c) {
      s16x8 w;
#pragma unroll
      for (int j = 0; j < 8; ++j) w[j] = (short)f2bf(kk[c * 2 + (j >> 2)][j & 3]);
      *(s16x8*)&Klds[srow * HD + ((scolK + c * 8) ^ swK)] = w;
    }
#pragma unroll
    for (int dd = 0; dd < 4; ++dd) {
      const int d = vd0 + dd;
      s16x8 w;
#pragma unroll
      for (int r = 0; r < 8; ++r) w[r] = (short)f2bf(vv[r][dd]);
      *(s16x8*)&Vt[d * KVBLK + (vkv0 ^ swzV(d))] = w;
    }
  };

  f32x4 o[2][8];
  float m[2][4], ls[2][4];
  auto resetState = [&]() {
#pragma unroll
    for (int st = 0; st < 2; ++st) {
#pragma unroll
      for (int dt = 0; dt < 8; ++dt) { f32x4 z = {0.f, 0.f, 0.f, 0.f}; o[st][dt] = z; }
#pragma unroll
      for (int r = 0; r < 4; ++r) { m[st][r] = -__builtin_inff(); ls[st][r] = 0.f; }
    }
  };
  auto writeO = [&](int qw) {
#pragma unroll
    for (int st = 0; st < 2; ++st) {
      float rl[4];
#pragma unroll
      for (int r = 0; r < 4; ++r) rl[r] = 1.f / ls[st][r];
#pragma unroll
      for (int dt = 0; dt < 8; ++dt)
#pragma unroll
        for (int r = 0; r < 4; ++r) {
          int row = qw + st * 16 + hi * 4 + r;
          og[((size_t)h * S + row) * HD + dt * 16 + col] = o[st][dt][r] * rl[r];
        }
    }
  };

  auto kvt = [&](int i) { return (i < nt0) ? i : (i - nt0); };

  loadQ(qw0);
  resetState();
  loadKV(doc0 + kvt(0) * KVBLK);

  for (int i = 0; i < total; ++i) {
    __syncthreads();           // previous tile fully consumed
    stage();
    __syncthreads();

    // prefetch next tile into regs (consumed after two syncs next iter)
    if (i + 1 < total) loadKV(doc0 + kvt(i + 1) * KVBLK);

    // ---- QK^T: S[32q x 64k] ----
    f32x4 sA[2][4];
#pragma unroll
    for (int kt = 0; kt < 4; ++kt) {
      const int r = kt * 16 + col;
      const int swr = (r & 7) << 3;
      s16x8 kf[4];
#pragma unroll
      for (int dc = 0; dc < 4; ++dc)
        kf[dc] = *(const s16x8*)&Klds[r * HD + ((dc * 32 + hi * 8) ^ swr)];
      __builtin_amdgcn_s_setprio(1);
#pragma unroll
      for (int st = 0; st < 2; ++st) {
        f32x4 acc = {0.f, 0.f, 0.f, 0.f};
#pragma unroll
        for (int dc = 0; dc < 4; ++dc)
          acc = __builtin_amdgcn_mfma_f32_16x16x32_bf16(qf[st][dc], kf[dc], acc, 0, 0, 0);
        sA[st][kt] = acc;
      }
      __builtin_amdgcn_s_setprio(0);
    }

    // diagonal masking (one diag tile per phase; moff handles odd q-tiles)
    if (i == nt0 - 1 || i == total - 1) {
      const int moff = (i == nt0 - 1) ? moff0 : moff1;
#pragma unroll
      for (int st = 0; st < 2; ++st)
#pragma unroll
        for (int kt = 0; kt < 4; ++kt)
#pragma unroll
          for (int r = 0; r < 4; ++r) {
            int qr = st * 16 + hi * 4 + r;
            int kc = kt * 16 + col;
            if (kc > qr + moff) sA[st][kt][r] = -__builtin_inff();
          }
    }

    // ---- online softmax with defer-max ----
#pragma unroll
    for (int st = 0; st < 2; ++st) {
      float pm[4], ps[4];
#pragma unroll
      for (int r = 0; r < 4; ++r)
        pm[r] = fmaxf(fmaxf(sA[st][0][r], sA[st][1][r]), fmaxf(sA[st][2][r], sA[st][3][r]));
#pragma unroll
      for (int off = 1; off < 16; off <<= 1)
#pragma unroll
        for (int r = 0; r < 4; ++r) pm[r] = fmaxf(pm[r], __shfl_xor(pm[r], off));

      int need = 0;
#pragma unroll
      for (int r = 0; r < 4; ++r) need |= (pm[r] > m[st][r] + THR) ? 1 : 0;
      if (__any(need)) {
#pragma unroll
        for (int r = 0; r < 4; ++r) {
          float mn = fmaxf(m[st][r], pm[r]);
          float corr = __builtin_amdgcn_exp2f((m[st][r] - mn) * cs);
          m[st][r] = mn;
          ls[st][r] *= corr;
#pragma unroll
          for (int dt = 0; dt < 8; ++dt) o[st][dt][r] *= corr;
        }
      }
#pragma unroll
      for (int r = 0; r < 4; ++r) {
        float sum = 0.f;
#pragma unroll
        for (int kt = 0; kt < 4; ++kt) {
          float p = __builtin_amdgcn_exp2f((sA[st][kt][r] - m[st][r]) * cs);
          sA[st][kt][r] = p;
          sum += p;
        }
        ps[r] = sum;
      }
#pragma unroll
      for (int off = 1; off < 16; off <<= 1)
#pragma unroll
        for (int r = 0; r < 4; ++r) ps[r] += __shfl_xor(ps[r], off);
#pragma unroll
      for (int r = 0; r < 4; ++r) ls[st][r] += ps[r];
#pragma unroll
      for (int r = 0; r < 4; ++r) {
        int q = st * 16 + hi * 4 + r;
        int xq = ((q >> 1) & 7) << 3;
        ushort* dst = &Plds[wid][q * KVBLK];
        dst[(col)      ^ xq] = f2bf(sA[st][0][r]);
        dst[(16 + col) ^ xq] = f2bf(sA[st][1][r]);
        dst[(32 + col) ^ xq] = f2bf(sA[st][2][r]);
        dst[(48 + col) ^ xq] = f2bf(sA[st][3][r]);
      }
    }

    asm volatile("s_waitcnt lgkmcnt(0)" ::: "memory");  // wave-local P visibility
    __builtin_amdgcn_sched_barrier(0);                  // rule #18

    // ---- PV ----
    s16x8 af[2][2];
#pragma unroll
    for (int st = 0; st < 2; ++st) {
      int q2 = st * 16 + col;
      int xq = ((q2 >> 1) & 7) << 3;
#pragma unroll
      for (int ksb = 0; ksb < 2; ++ksb)
        af[st][ksb] = *(const s16x8*)&Plds[wid][q2 * KVBLK + ((ksb * 32 + hi * 8) ^ xq)];
    }
#pragma unroll
    for (int dt = 0; dt < 8; ++dt) {
      int d2 = dt * 16 + col;
      int xv = swzV(d2);
#pragma unroll
      for (int ksb = 0; ksb < 2; ++ksb) {
        s16x8 vf = *(const s16x8*)&Vt[d2 * KVBLK + ((ksb * 32 + hi * 8) ^ xv)];
        __builtin_amdgcn_s_setprio(1);
#pragma unroll
        for (int st = 0; st < 2; ++st)
          o[st][dt] = __builtin_amdgcn_mfma_f32_16x16x32_bf16(af[st][ksb], vf, o[st][dt], 0, 0, 0);
        __builtin_amdgcn_s_setprio(0);
      }
    }

    // phase boundary: flush q-tile 0, switch to q-tile 1
    if (i == nt0 - 1) {
      writeO(qw0);
      resetState();
      loadQ(qw1);
    }
  }

  writeO(qw1);
}

extern "C" void kernel_launch(void* const* d_in, const int* in_sizes, int n_in,
                              void* d_out, int out_size, void* d_ws, size_t ws_size,
                              hipStream_t stream) {
  const float* q = (const float*)d_in[0];
  const float* k = (const float*)d_in[1];
  const float* v = (const float*)d_in[2];
  float* out = (float*)d_out;
  const int S  = in_sizes[1] / (NKVH * HD);   // 4096
  const int nd = in_sizes[3] - 1;             // 4
  const int L  = S / nd;                      // 1024
  const int nblk = (S / (2 * QBLK)) * NKVH;   // 512 -> 2 blocks/CU co-resident
  attn_doc_causal<<<nblk, 256, 0, stream>>>(q, k, v, out, S, L);
}

// Round 6
// 129.596 us; speedup vs baseline: 2.6217x; 2.6217x over previous
//
#include <hip/hip_runtime.h>
#include <hip/hip_bf16.h>
#include <stdint.h>

typedef short s16x4 __attribute__((ext_vector_type(4)));
typedef short s16x8 __attribute__((ext_vector_type(8)));
typedef float f32x4 __attribute__((ext_vector_type(4)));

#define NH    32
#define NKVH  8
#define GQ    4
#define HD    128
#define QBLK  32     // q rows per block; wave owns 16 rows (4 heads x 2 halves)
#define KVBLK 32

static __device__ __forceinline__ ushort f2bf(float f) {
  return __bfloat16_as_ushort(__float2bfloat16(f));
}

// XOR swizzle for 32-element (64B) bf16 rows, 8-element granule:
// quarter-wave b128 reads land 2 lanes per 16B slot (free, m136).
static __device__ __forceinline__ int swz32(int x) {
  return (((x >> 1) ^ (x >> 3)) & 3) << 3;
}

__global__ void __launch_bounds__(512, 4)
attn_doc_causal(const float* __restrict__ qg, const float* __restrict__ kg,
                const float* __restrict__ vg, float* __restrict__ og,
                int S, int L) {
  __shared__ ushort Klds[KVBLK * HD];      // [kv][d], ^((kv&7)<<3) on 8-elem granule
  __shared__ ushort Vt[HD * KVBLK];        // [d][kv], ^swz32(d)
  __shared__ ushort Plds[8][16 * KVBLK];   // per-wave [q][kv], ^swz32(q)

  const int tid  = threadIdx.x;
  const int lane = tid & 63;
  const int wid  = tid >> 6;
  const int col  = lane & 15;
  const int hi   = lane >> 4;
  const int hq   = wid & 3;                // GQA head in group
  const int qh   = wid >> 2;               // 16-row half of the 32-row q tile
  const int bid  = blockIdx.x;
  const int kvh  = bid & 7;                // head-aligned XCD mapping
  const int nq   = L / QBLK;               // 32
  const int npair= nq >> 1;                // 16
  const int pidx = bid >> 3;
  const int doc  = pidx / npair;
  const int ipr  = pidx % npair;
  const int doc0 = doc * L;
  const int h    = kvh * GQ + hq;

  const int qt0   = nq - 1 - ipr;          // big strip first
  const int qt1   = ipr;
  const int nt0   = qt0 + 1;               // KVBLK == QBLK
  const int total = nt0 + qt1 + 1;         // == 33, uniform
  const int qw0   = doc0 + qt0 * QBLK + qh * 16;
  const int qw1   = doc0 + qt1 * QBLK + qh * 16;

  const float cs  = 0.08838834764831845f * 1.4426950408889634f;  // SCALE*log2(e)
  const float THR = 62.0f;                 // raw-score defer-max threshold (~8 in exp2 units)

  // staging assignments (512 threads move 16KB K + 16KB V per tile)
  const int srow  = tid >> 4;              // K row 0..31
  const int scolK = (tid & 15) << 3;       // K col0, 8 floats per thread
  const int d0v   = (tid & 63) << 1;       // V: 2 d's per thread
  const int vkv0  = (tid >> 6) << 2;       // V: 4 kv rows per thread (per wave)
  const size_t kvstr = (size_t)(NKVH * HD);

  s16x8 qf[4];
  auto loadQ = [&](int qw) {
    const float* qrow = qg + (size_t)(qw + col) * (NH * HD) + h * HD + hi * 8;
#pragma unroll
    for (int dc = 0; dc < 4; ++dc) {
      float4 x = ((const float4*)(qrow + dc * 32))[0];
      float4 y = ((const float4*)(qrow + dc * 32))[1];
      s16x8 f;
      f[0] = (short)f2bf(x.x); f[1] = (short)f2bf(x.y);
      f[2] = (short)f2bf(x.z); f[3] = (short)f2bf(x.w);
      f[4] = (short)f2bf(y.x); f[5] = (short)f2bf(y.y);
      f[6] = (short)f2bf(y.z); f[7] = (short)f2bf(y.w);
      qf[dc] = f;
    }
  };

  // prefetch registers: 16 f32 total (fits the 128-VGPR budget)
  float4 ka, kb;
  float2 va, vb, vc, vd;
  auto loadKV = [&](int r0) {
    const float* ks = kg + (size_t)(r0 + srow) * kvstr + kvh * HD + scolK;
    ka = ((const float4*)ks)[0];
    kb = ((const float4*)ks)[1];
    const float* vs = vg + (size_t)kvh * HD + d0v;
    va = *(const float2*)(vs + (size_t)(r0 + vkv0 + 0) * kvstr);
    vb = *(const float2*)(vs + (size_t)(r0 + vkv0 + 1) * kvstr);
    vc = *(const float2*)(vs + (size_t)(r0 + vkv0 + 2) * kvstr);
    vd = *(const float2*)(vs + (size_t)(r0 + vkv0 + 3) * kvstr);
  };

  auto stage = [&]() {
    const int swK = (srow & 7) << 3;
    s16x8 w;
    w[0] = (short)f2bf(ka.x); w[1] = (short)f2bf(ka.y);
    w[2] = (short)f2bf(ka.z); w[3] = (short)f2bf(ka.w);
    w[4] = (short)f2bf(kb.x); w[5] = (short)f2bf(kb.y);
    w[6] = (short)f2bf(kb.z); w[7] = (short)f2bf(kb.w);
    *(s16x8*)&Klds[srow * HD + (scolK ^ swK)] = w;
    s16x4 w0, w1;
    w0[0] = (short)f2bf(va.x); w0[1] = (short)f2bf(vb.x);
    w0[2] = (short)f2bf(vc.x); w0[3] = (short)f2bf(vd.x);
    w1[0] = (short)f2bf(va.y); w1[1] = (short)f2bf(vb.y);
    w1[2] = (short)f2bf(vc.y); w1[3] = (short)f2bf(vd.y);
    *(s16x4*)&Vt[(d0v + 0) * KVBLK + (vkv0 ^ swz32(d0v + 0))] = w0;
    *(s16x4*)&Vt[(d0v + 1) * KVBLK + (vkv0 ^ swz32(d0v + 1))] = w1;
  };

  f32x4 o[8];
  float m[4], ls[4];
  auto resetState = [&]() {
#pragma unroll
    for (int dt = 0; dt < 8; ++dt) { f32x4 z = {0.f, 0.f, 0.f, 0.f}; o[dt] = z; }
#pragma unroll
    for (int r = 0; r < 4; ++r) { m[r] = -__builtin_inff(); ls[r] = 0.f; }
  };
  auto writeO = [&](int qw) {
    float rl[4];
#pragma unroll
    for (int r = 0; r < 4; ++r) rl[r] = 1.f / ls[r];
#pragma unroll
    for (int dt = 0; dt < 8; ++dt)
#pragma unroll
      for (int r = 0; r < 4; ++r) {
        int row = qw + hi * 4 + r;
        og[((size_t)h * S + row) * HD + dt * 16 + col] = o[dt][r] * rl[r];
      }
  };

  auto kvt = [&](int i) { return (i < nt0) ? i : (i - nt0); };

  loadQ(qw0);
  resetState();
  loadKV(doc0);

  for (int i = 0; i < total; ++i) {
    __syncthreads();            // previous tile fully consumed
    stage();
    __syncthreads();

    // prefetch next tile into regs (consumed after two syncs next iter)
    if (i + 1 < total) loadKV(doc0 + kvt(i + 1) * KVBLK);

    // ---- QK^T: S[16q x 32k] per wave ----
    f32x4 sA[2];
#pragma unroll
    for (int kt = 0; kt < 2; ++kt) {
      const int r = kt * 16 + col;
      const int swr = (r & 7) << 3;
      s16x8 kf[4];
#pragma unroll
      for (int dc = 0; dc < 4; ++dc)
        kf[dc] = *(const s16x8*)&Klds[r * HD + ((dc * 32 + hi * 8) ^ swr)];
      __builtin_amdgcn_s_setprio(1);
      f32x4 acc = {0.f, 0.f, 0.f, 0.f};
#pragma unroll
      for (int dc = 0; dc < 4; ++dc)
        acc = __builtin_amdgcn_mfma_f32_16x16x32_bf16(qf[dc], kf[dc], acc, 0, 0, 0);
      __builtin_amdgcn_s_setprio(0);
      sA[kt] = acc;
    }

    // diagonal tile masking (KVBLK==QBLK: diag iter = last of each phase)
    if (i == nt0 - 1 || i == total - 1) {
      const int moff = qh * 16;
#pragma unroll
      for (int kt = 0; kt < 2; ++kt)
#pragma unroll
        for (int r = 0; r < 4; ++r) {
          int qr = hi * 4 + r + moff;
          int kc = kt * 16 + col;
          if (kc > qr) sA[kt][r] = -__builtin_inff();
        }
    }

    // ---- online softmax with defer-max ----
    {
      float pm[4], ps[4];
#pragma unroll
      for (int r = 0; r < 4; ++r) pm[r] = fmaxf(sA[0][r], sA[1][r]);
#pragma unroll
      for (int off = 1; off < 16; off <<= 1)
#pragma unroll
        for (int r = 0; r < 4; ++r) pm[r] = fmaxf(pm[r], __shfl_xor(pm[r], off));

      int need = 0;
#pragma unroll
      for (int r = 0; r < 4; ++r) need |= (pm[r] > m[r] + THR) ? 1 : 0;
      if (__any(need)) {
#pragma unroll
        for (int r = 0; r < 4; ++r) {
          float mn = fmaxf(m[r], pm[r]);
          float corr = __builtin_amdgcn_exp2f((m[r] - mn) * cs);
          m[r] = mn;
          ls[r] *= corr;
#pragma unroll
          for (int dt = 0; dt < 8; ++dt) o[dt][r] *= corr;
        }
      }
#pragma unroll
      for (int r = 0; r < 4; ++r) {
        float p0 = __builtin_amdgcn_exp2f((sA[0][r] - m[r]) * cs);
        float p1 = __builtin_amdgcn_exp2f((sA[1][r] - m[r]) * cs);
        sA[0][r] = p0; sA[1][r] = p1;
        ps[r] = p0 + p1;
      }
#pragma unroll
      for (int off = 1; off < 16; off <<= 1)
#pragma unroll
        for (int r = 0; r < 4; ++r) ps[r] += __shfl_xor(ps[r], off);
#pragma unroll
      for (int r = 0; r < 4; ++r) ls[r] += ps[r];
#pragma unroll
      for (int r = 0; r < 4; ++r) {
        int q = hi * 4 + r;
        int xq = swz32(q);
        ushort* dst = &Plds[wid][q * KVBLK];
        dst[(col)      ^ xq] = f2bf(sA[0][r]);
        dst[(16 + col) ^ xq] = f2bf(sA[1][r]);
      }
    }

    asm volatile("s_waitcnt lgkmcnt(0)" ::: "memory");  // wave-local P visibility
    __builtin_amdgcn_sched_barrier(0);                  // rule #18

    // ---- PV: O[16q x 128d] += P[16q x 32k] * V[32k x 128d] ----
    {
      const int xq2 = swz32(col);
      s16x8 af = *(const s16x8*)&Plds[wid][col * KVBLK + ((hi * 8) ^ xq2)];
      __builtin_amdgcn_s_setprio(1);
#pragma unroll
      for (int dt = 0; dt < 8; ++dt) {
        int d2 = dt * 16 + col;
        s16x8 vf = *(const s16x8*)&Vt[d2 * KVBLK + ((hi * 8) ^ swz32(d2))];
        o[dt] = __builtin_amdgcn_mfma_f32_16x16x32_bf16(af, vf, o[dt], 0, 0, 0);
      }
      __builtin_amdgcn_s_setprio(0);
    }

    // phase boundary: flush q-tile 0, switch to q-tile 1
    if (i == nt0 - 1) {
      writeO(qw0);
      resetState();
      loadQ(qw1);
    }
  }

  writeO(qw1);
}

extern "C" void kernel_launch(void* const* d_in, const int* in_sizes, int n_in,
                              void* d_out, int out_size, void* d_ws, size_t ws_size,
                              hipStream_t stream) {
  const float* q = (const float*)d_in[0];
  const float* k = (const float*)d_in[1];
  const float* v = (const float*)d_in[2];
  float* out = (float*)d_out;
  const int S  = in_sizes[1] / (NKVH * HD);   // 4096
  const int nd = in_sizes[3] - 1;             // 4
  const int L  = S / nd;                      // 1024
  const int nblk = (S / (2 * QBLK)) * NKVH;   // 512 -> 2 blocks/CU co-resident
  attn_doc_causal<<<nblk, 512, 0, stream>>>(q, k, v, out, S, L);
}

// Round 8
// 88.269 us; speedup vs baseline: 3.8492x; 1.4682x over previous
//
#include <hip/hip_runtime.h>
#include <hip/hip_bf16.h>
#include <stdint.h>

typedef short s16x8 __attribute__((ext_vector_type(8)));
typedef float f32x4 __attribute__((ext_vector_type(4)));
typedef uint32_t u32;
typedef u32 u32x4 __attribute__((ext_vector_type(4)));

#define NH    32
#define NKVH  8
#define GQ    4
#define HD    128
#define QBLK  32
#define KVBLK 32

static __device__ __forceinline__ ushort f2bf(float f) {
  return __bfloat16_as_ushort(__float2bfloat16(f));
}
static __device__ __forceinline__ u32 pk2(float lo, float hi) {
  return (u32)f2bf(lo) | ((u32)f2bf(hi) << 16);
}

__global__ void __launch_bounds__(512, 4)
attn_doc_causal(const float* __restrict__ qg, const float* __restrict__ kg,
                const float* __restrict__ vg, float* __restrict__ og,
                int S, int L) {
  __shared__ ushort Klds[KVBLK * HD];   // [kv][d], ^((kv&7)<<3), 8KB
  __shared__ ushort Vt2[64 * 64];       // packed V^T, 8KB: row=(d>>1),
                                        // elem=(d&1)*32 + (kv ^ (((d>>1)&3)<<3))

  const int tid  = threadIdx.x;
  const int lane = tid & 63;
  const int wid  = tid >> 6;
  const int col  = lane & 15;
  const int hi   = lane >> 4;
  const int hq   = wid & 3;                // GQA head in group
  const int qh   = wid >> 2;               // 16-row half of q tile
  const int bid  = blockIdx.x;
  const int kvh  = bid & 7;                // head-aligned XCD mapping
  const int nq   = L / QBLK;               // 32
  const int npair= nq >> 1;                // 16
  const int pidx = bid >> 3;
  const int doc  = pidx / npair;
  const int ipr  = pidx % npair;
  const int doc0 = doc * L;
  const int h    = kvh * GQ + hq;

  const int qt0   = nq - 1 - ipr;
  const int qt1   = ipr;
  const int nt0   = qt0 + 1;
  const int total = nt0 + qt1 + 1;         // 33, uniform
  const int qw0   = doc0 + qt0 * QBLK + qh * 16;
  const int qw1   = doc0 + qt1 * QBLK + qh * 16;

  const float cs  = 0.08838834764831845f * 1.4426950408889634f;  // SCALE*log2(e)
  const float THR = 62.0f;

  // K staging: thread = (row, 8 cols)
  const int srow  = tid >> 4;
  const int scolK = (tid & 15) << 3;
  // V staging: thread = 1 d x 8 kv (b128, conflict-free quad-XOR layout)
  const int dv    = tid >> 2;              // 0..127
  const int kvq   = tid & 3;
  const int vwoff = (dv >> 1) * 64 + (dv & 1) * 32 + ((kvq ^ ((dv >> 1) & 3)) << 3);
  const int vrbase = (col >> 1) * 64 + (col & 1) * 32 + ((hi ^ ((col >> 1) & 3)) << 3);

  const size_t kvstr = (size_t)(NKVH * HD);

  s16x8 qf[4];
  auto loadQ = [&](int qw) {
    const float* qrow = qg + (size_t)(qw + col) * (NH * HD) + h * HD + hi * 8;
#pragma unroll
    for (int dc = 0; dc < 4; ++dc) {
      float4 x = ((const float4*)(qrow + dc * 32))[0];
      float4 y = ((const float4*)(qrow + dc * 32))[1];
      s16x8 f;
      f[0] = (short)f2bf(x.x); f[1] = (short)f2bf(x.y);
      f[2] = (short)f2bf(x.z); f[3] = (short)f2bf(x.w);
      f[4] = (short)f2bf(y.x); f[5] = (short)f2bf(y.y);
      f[6] = (short)f2bf(y.z); f[7] = (short)f2bf(y.w);
      qf[dc] = f;
    }
  };

  float4 ka, kb;
  float vvv[8];
  auto loadKV = [&](int r0) {
    const float* ks = kg + (size_t)(r0 + srow) * kvstr + kvh * HD + scolK;
    ka = ((const float4*)ks)[0];
    kb = ((const float4*)ks)[1];
    const float* vs = vg + (size_t)kvh * HD + dv;
#pragma unroll
    for (int j = 0; j < 8; ++j)
      vvv[j] = vs[(size_t)(r0 + kvq * 8 + j) * kvstr];
  };

  auto stage = [&]() {
    const int swK = (srow & 7) << 3;
    s16x8 w;
    w[0] = (short)f2bf(ka.x); w[1] = (short)f2bf(ka.y);
    w[2] = (short)f2bf(ka.z); w[3] = (short)f2bf(ka.w);
    w[4] = (short)f2bf(kb.x); w[5] = (short)f2bf(kb.y);
    w[6] = (short)f2bf(kb.z); w[7] = (short)f2bf(kb.w);
    *(s16x8*)&Klds[srow * HD + (scolK ^ swK)] = w;
    s16x8 v;
#pragma unroll
    for (int j = 0; j < 8; ++j) v[j] = (short)f2bf(vvv[j]);
    *(s16x8*)&Vt2[vwoff] = v;
  };

  f32x4 o[8];
  float m, ls;
  auto resetState = [&]() {
#pragma unroll
    for (int dt = 0; dt < 8; ++dt) { f32x4 z = {0.f, 0.f, 0.f, 0.f}; o[dt] = z; }
    m = -__builtin_inff(); ls = 0.f;
  };
  auto writeO = [&](int qw) {
    float rl[4];
#pragma unroll
    for (int r = 0; r < 4; ++r)
      rl[r] = 1.f / __shfl(ls, (hi << 4) | ((hi << 2) + r));
#pragma unroll
    for (int dt = 0; dt < 8; ++dt)
#pragma unroll
      for (int r = 0; r < 4; ++r) {
        int row = qw + hi * 4 + r;
        og[((size_t)h * S + row) * HD + dt * 16 + col] = o[dt][r] * rl[r];
      }
  };

  auto kvt = [&](int i) { return (i < nt0) ? i : (i - nt0); };

  loadQ(qw0);
  resetState();
  loadKV(doc0);

  for (int i = 0; i < total; ++i) {
    __syncthreads();            // previous tile fully consumed
    stage();
    __syncthreads();

    if (i + 1 < total) loadKV(doc0 + kvt(i + 1) * KVBLK);

    // ---- QK^T swapped: S^T[k][q] = mfma(A=K, B=Q); q = lane&15 ----
    f32x4 sA[2];
#pragma unroll
    for (int kt = 0; kt < 2; ++kt) {
      const int r = kt * 16 + col;
      const int swr = (r & 7) << 3;
      s16x8 kf[4];
#pragma unroll
      for (int dc = 0; dc < 4; ++dc)
        kf[dc] = *(const s16x8*)&Klds[r * HD + ((dc * 32 + hi * 8) ^ swr)];
      __builtin_amdgcn_s_setprio(1);
      f32x4 acc = {0.f, 0.f, 0.f, 0.f};
#pragma unroll
      for (int dc = 0; dc < 4; ++dc)
        acc = __builtin_amdgcn_mfma_f32_16x16x32_bf16(kf[dc], qf[dc], acc, 0, 0, 0);
      __builtin_amdgcn_s_setprio(0);
      sA[kt] = acc;
    }

    // diagonal masking: element (k = kt*16 + 4hi + r, q = qh*16 + col)
    if (i == nt0 - 1 || i == total - 1) {
      const int qloc = qh * 16 + col;
#pragma unroll
      for (int kt = 0; kt < 2; ++kt)
#pragma unroll
        for (int r = 0; r < 4; ++r) {
          int kc = kt * 16 + hi * 4 + r;
          if (kc > qloc) sA[kt][r] = -__builtin_inff();
        }
    }

    // ---- softmax: row lane-local; allreduce over hi via shfl_xor ----
    float pm = fmaxf(fmaxf(fmaxf(sA[0][0], sA[0][1]), fmaxf(sA[0][2], sA[0][3])),
                     fmaxf(fmaxf(sA[1][0], sA[1][1]), fmaxf(sA[1][2], sA[1][3])));
    pm = fmaxf(pm, __shfl_xor(pm, 16));
    pm = fmaxf(pm, __shfl_xor(pm, 32));
    int need = (pm > m + THR) ? 1 : 0;
    if (__any(need)) {                    // defer-max (T13)
      float mn = fmaxf(m, pm);
      float corr = __builtin_amdgcn_exp2f((m - mn) * cs);
      m = mn; ls *= corr;
#pragma unroll
      for (int r = 0; r < 4; ++r) {
        float cr = __shfl(corr, (hi << 4) | ((hi << 2) + r));   // corr of q=4hi+r
#pragma unroll
        for (int dt = 0; dt < 8; ++dt) o[dt][r] *= cr;
      }
    }
    float ps = 0.f;
#pragma unroll
    for (int kt = 0; kt < 2; ++kt)
#pragma unroll
      for (int r = 0; r < 4; ++r) {
        float p = __builtin_amdgcn_exp2f((sA[kt][r] - m) * cs);
        sA[kt][r] = p;
        ps += p;
      }
    ps += __shfl_xor(ps, 16);
    ps += __shfl_xor(ps, 32);
    ls += ps;

    // ---- P -> A-frag: 8 shfl pulls + target-side select (verified mapping) ----
    // lane holds P[k=kt*16+4hi+r][q=col]; A-frag needs P[k=8hi+j][q=col].
    u32 x0 = pk2(sA[0][0], sA[0][1]);     // kt=0 pairs (4hi, 4hi+1)
    u32 x1 = pk2(sA[0][2], sA[0][3]);     // kt=0 pairs (4hi+2, 4hi+3)
    u32 y0 = pk2(sA[1][0], sA[1][1]);     // kt=1
    u32 y1 = pk2(sA[1][2], sA[1][3]);
    const int s0 = col | ((hi & 1) << 5); // source lane h' = 2*(hi&1)
    const int s1 = s0 | 16;               // source lane h' = 2*(hi&1)+1
    u32 e00 = __shfl(x0, s0), e01 = __shfl(y0, s0);
    u32 e10 = __shfl(x1, s0), e11 = __shfl(y1, s0);
    u32 e20 = __shfl(x0, s1), e21 = __shfl(y0, s1);
    u32 e30 = __shfl(x1, s1), e31 = __shfl(y1, s1);
    const bool lo2 = (hi < 2);            // hi<2 takes kt=0 words, else kt=1
    u32x4 avec = { lo2 ? e00 : e01, lo2 ? e10 : e11,
                   lo2 ? e20 : e21, lo2 ? e30 : e31 };
    s16x8 af = __builtin_bit_cast(s16x8, avec);

    // ---- PV: O[q][d] += P^T * V ----
    __builtin_amdgcn_s_setprio(1);
#pragma unroll
    for (int dt = 0; dt < 8; ++dt) {
      s16x8 vf = *(const s16x8*)&Vt2[dt * 512 + vrbase];
      o[dt] = __builtin_amdgcn_mfma_f32_16x16x32_bf16(af, vf, o[dt], 0, 0, 0);
    }
    __builtin_amdgcn_s_setprio(0);

    // phase boundary
    if (i == nt0 - 1) {
      writeO(qw0);
      resetState();
      loadQ(qw1);
    }
  }

  writeO(qw1);
}

extern "C" void kernel_launch(void* const* d_in, const int* in_sizes, int n_in,
                              void* d_out, int out_size, void* d_ws, size_t ws_size,
                              hipStream_t stream) {
  const float* q = (const float*)d_in[0];
  const float* k = (const float*)d_in[1];
  const float* v = (const float*)d_in[2];
  float* out = (float*)d_out;
  const int S  = in_sizes[1] / (NKVH * HD);   // 4096
  const int nd = in_sizes[3] - 1;             // 4
  const int L  = S / nd;                      // 1024
  const int nblk = (S / (2 * QBLK)) * NKVH;   // 512 -> 2 blocks/CU
  attn_doc_causal<<<nblk, 512, 0, stream>>>(q, k, v, out, S, L);
}